// Round 7
// baseline (621.528 us; speedup 1.0000x reference)
//
#include <hip/hip_runtime.h>

#define BATCH 2048
#define NB 254

__device__ __forceinline__ float selw(int pd, float w0, float w1, float w2, float w3) {
    return (pd == 0) ? w0 : (pd == 1) ? w1 : (pd == 2) ? w2 : (pd == 3) ? w3 : 0.f;
}

// Per (b,i): silu(x)*wb, 4 spline tap weights *ws (shifted into clamped window), window start j.
// Invalid (x outside grid) -> js = -1 (accum skips the taps; spline contributes 0).
// TR: input activation layout. false: act[b][IN] (layer-0 x). true: act[i][BATCH] (transposed hidden).
template<bool TR>
__global__ __launch_bounds__(256) void basis_kernel(
    const float* __restrict__ act, int IN,
    const float* __restrict__ wbp, const float* __restrict__ wsp,
    float2* __restrict__ sjbuf, float4* __restrict__ vbuf)
{
    int idx = blockIdx.x * 256 + threadIdx.x;
    int total = BATCH * IN;
    if (idx >= total) return;
    int i = idx / BATCH;
    int b = idx - i * BATCH;

    float x = TR ? act[idx] : act[(size_t)b * IN + i];
    float wb = wbp[0], wsc = wsp[0];

    float sil = x / (1.f + __expf(-x));

    const float LO = -0.05f;
    const float INVH = 228.18181818181818f;  // 251/1.1
    float uf = (x - LO) * INVH;
    float fm = floorf(uf);
    float t = uf - fm;
    int M = (int)fm + 3;     // grid interval index: x in [GRID[M], GRID[M+1])

    bool valid = (M >= 0) && (M <= 256);

    float omt = 1.f - t;
    float t2 = t * t, t3 = t2 * t;
    const float S = 1.f / 6.f;
    float w0 = omt * omt * omt * S * wsc;
    float w1 = (3.f * t3 - 6.f * t2 + 4.f) * S * wsc;
    float w2 = (-3.f * t3 + 3.f * t2 + 3.f * t + 1.f) * S * wsc;
    float w3 = t3 * S * wsc;

    int js = M - 3;
    js = js < 0 ? 0 : js;
    js = js > (NB - 4) ? (NB - 4) : js;
    int d = js - (M - 3);    // shift of taps inside the clamped window, in [-3,3]

    float vp0 = selw(0 + d, w0, w1, w2, w3);
    float vp1 = selw(1 + d, w0, w1, w2, w3);
    float vp2 = selw(2 + d, w0, w1, w2, w3);
    float vp3 = selw(3 + d, w0, w1, w2, w3);

    if (!valid) js = -1;     // signal: no spline contribution

    sjbuf[idx] = make_float2(sil * wb, __int_as_float(js));
    vbuf[idx] = make_float4(vp0, vp1, vp2, vp3);
}

// LDS-staged accum.
// Block: 128 b-lanes (x) * 8 o-rows (y) = 1024 threads, 16 waves (each wave: one o, 64 b's).
// Grid: (BATCH/128, 256/8) = (16, 32) = 512 blocks = 2 per CU (32 waves/CU).
// Per i-step: stage the 8 rows sw[o0+g][i][0..253] into LDS (double-buffered, coalesced
// float2 loads), then each thread reads its 4 taps from LDS (random-j ds_read_b32,
// bank-pass cost) and FMAs into its private register accumulator.
// out/resid in transposed [o][BATCH] layout.
template<int IN, bool RES>
__global__ __launch_bounds__(1024) void accum_lds(
    const float2* __restrict__ sjbuf,   // [i][BATCH]
    const float4* __restrict__ vbuf,    // [i][BATCH]
    const float* __restrict__ bw,       // [o][IN]
    const float* __restrict__ sw,       // [o][IN][254]
    const float* __restrict__ resid,    // [o][BATCH]
    float* __restrict__ out)            // [o][BATCH]
{
    int bx = threadIdx.x;               // 0..127
    int g  = threadIdx.y;               // 0..7
    int b  = blockIdx.x * 128 + bx;
    int o  = blockIdx.y * 8 + g;

    __shared__ float rows[2][8][256];   // 16 KB, rows padded 254->256

    // walking pointers
    const float*  swrow = sw + (size_t)o * IN * NB;        // row (o, i=0)
    const float*  bwp   = bw + (size_t)o * IN;
    const float2* sjp   = sjbuf + b;
    const float4* vvp   = vbuf + b;

    // prologue: stage i = 0
    if (bx < 127) {
        float2 st = *(const float2*)(swrow + 2 * bx);
        rows[0][g][2 * bx]     = st.x;
        rows[0][g][2 * bx + 1] = st.y;
    }
    __syncthreads();

    float acc = 0.f;

    for (int i = 0; i < IN; i++) {
        int cur = i & 1, nxt = cur ^ 1;

        // issue next row's staging loads early (latency hides under compute)
        float2 nst;
        bool do_stage = (i + 1 < IN) && (bx < 127);
        if (do_stage)
            nst = *(const float2*)(swrow + NB + 2 * bx);

        // record for (b, i)
        float2 sj = sjp[(size_t)i * BATCH];
        int j = __float_as_int(sj.y);

        // base path (bw address is wave-uniform)
        acc += sj.x * bwp[i];

        // spline path from LDS
        if (j >= 0) {
            float4 v = vvp[(size_t)i * BATCH];
            const float* rp = &rows[cur][g][0];
            float t0 = rp[j], t1 = rp[j + 1], t2 = rp[j + 2], t3 = rp[j + 3];
            acc += v.x * t0 + v.y * t1 + v.z * t2 + v.w * t3;
        }

        // write next buffer, then barrier
        if (do_stage) {
            rows[nxt][g][2 * bx]     = nst.x;
            rows[nxt][g][2 * bx + 1] = nst.y;
        }
        swrow += NB;
        __syncthreads();
    }

    size_t oidx = (size_t)o * BATCH + b;
    float r = RES ? resid[oidx] : 0.f;
    out[oidx] = acc + r;
}

// Final layer: out=1, f32 weights. 64 lanes per batch row, shuffle-reduce.
__global__ __launch_bounds__(256) void out_kernel(
    const float2* __restrict__ sjbuf, const float4* __restrict__ vbuf,
    const float* __restrict__ bw, const float* __restrict__ sw,
    float* __restrict__ out)
{
    int tid = threadIdx.x;
    int bl = tid >> 6;
    int ig = tid & 63;
    int b = blockIdx.x * 4 + bl;

    float acc = 0.f;
    for (int ii = ig; ii < 256; ii += 64) {
        float2 sj = sjbuf[ii * BATCH + b];
        int j = __float_as_int(sj.y);
        acc += sj.x * bw[ii];
        if (j >= 0) {
            float4 v = vbuf[ii * BATCH + b];
            const float* p = sw + (size_t)ii * NB + j;
            acc += v.x * p[0] + v.y * p[1] + v.z * p[2] + v.w * p[3];
        }
    }
#pragma unroll
    for (int dlt = 32; dlt >= 1; dlt >>= 1) acc += __shfl_down(acc, dlt, 64);
    if (ig == 0) out[b] = acc;
}

extern "C" void kernel_launch(void* const* d_in, const int* in_sizes, int n_in,
                              void* d_out, int out_size, void* d_ws, size_t ws_size,
                              hipStream_t stream)
{
    const float* x   = (const float*)d_in[0];
    const float* bw0 = (const float*)d_in[1];
    const float* sw0 = (const float*)d_in[2];
    const float* wb0 = (const float*)d_in[3];
    const float* ws0 = (const float*)d_in[4];
    const float* bw1 = (const float*)d_in[5];
    const float* sw1 = (const float*)d_in[6];
    const float* wb1 = (const float*)d_in[7];
    const float* ws1 = (const float*)d_in[8];
    const float* bw2 = (const float*)d_in[9];
    const float* sw2 = (const float*)d_in[10];
    const float* wb2 = (const float*)d_in[11];
    const float* ws2 = (const float*)d_in[12];
    const float* bw3 = (const float*)d_in[13];
    const float* sw3 = (const float*)d_in[14];
    const float* wb3 = (const float*)d_in[15];
    const float* ws3 = (const float*)d_in[16];

    char* ws = (char*)d_ws;
    float4* vbuf  = (float4*)(ws);                        // 8 MB
    float2* sjbuf = (float2*)(ws + 8  * 1024 * 1024);     // 4 MB
    float*  hA    = (float*)(ws + 12 * 1024 * 1024);      // 2 MB  ([o][b] layout)
    float*  hB    = (float*)(ws + 14 * 1024 * 1024);      // 2 MB  ([o][b] layout)

    float* out = (float*)d_out;

    dim3 ablk(128, 8);    // 1024 threads: 128 b-lanes x 8 o-rows
    dim3 agrd(16, 32);    // 16 b-tiles x 32 o-tiles = 512 blocks (2/CU)

    // Layer 0: 64 -> 256 (x is [b][64], all in-grid)
    basis_kernel<false><<<(BATCH * 64 + 255) / 256, 256, 0, stream>>>(x, 64, wb0, ws0, sjbuf, vbuf);
    accum_lds<64, false><<<agrd, ablk, 0, stream>>>(sjbuf, vbuf, bw0, sw0, nullptr, hA);

    // Layer 1: 256 -> 256, residual (hA is [o][b] == [i][b] for next layer)
    basis_kernel<true><<<(BATCH * 256 + 255) / 256, 256, 0, stream>>>(hA, 256, wb1, ws1, sjbuf, vbuf);
    accum_lds<256, true><<<agrd, ablk, 0, stream>>>(sjbuf, vbuf, bw1, sw1, hA, hB);

    // Layer 2: 256 -> 256, residual
    basis_kernel<true><<<(BATCH * 256 + 255) / 256, 256, 0, stream>>>(hB, 256, wb2, ws2, sjbuf, vbuf);
    accum_lds<256, true><<<agrd, ablk, 0, stream>>>(sjbuf, vbuf, bw2, sw2, hB, hA);

    // Layer 3: 256 -> 1
    basis_kernel<true><<<(BATCH * 256 + 255) / 256, 256, 0, stream>>>(hA, 256, wb3, ws3, sjbuf, vbuf);
    out_kernel<<<BATCH / 4, 256, 0, stream>>>(sjbuf, vbuf, bw3, sw3, out);
}

// Round 8
// 595.616 us; speedup vs baseline: 1.0435x; 1.0435x over previous
//
#include <hip/hip_runtime.h>

#define BATCH 2048
#define NB 254

typedef float f4u __attribute__((ext_vector_type(4), aligned(4)));
typedef float f2u __attribute__((ext_vector_type(2), aligned(4)));

__device__ __forceinline__ float selw(int pd, float w0, float w1, float w2, float w3) {
    return (pd == 0) ? w0 : (pd == 1) ? w1 : (pd == 2) ? w2 : (pd == 3) ? w3 : 0.f;
}

// Per (b,i): silu(x)*wb, 4 spline tap weights *ws (shifted into clamped window), window start j.
// Invalid (x outside grid) -> js = -1 (accum skips taps; spline contributes 0).
// TR: input activation layout. false: act[b][IN] (layer-0 x). true: act[i][BATCH] (transposed hidden).
template<bool TR>
__global__ __launch_bounds__(256) void basis_kernel(
    const float* __restrict__ act, int IN,
    const float* __restrict__ wbp, const float* __restrict__ wsp,
    float2* __restrict__ sjbuf, float4* __restrict__ vbuf)
{
    int idx = blockIdx.x * 256 + threadIdx.x;
    int total = BATCH * IN;
    if (idx >= total) return;
    int i = idx / BATCH;
    int b = idx - i * BATCH;

    float x = TR ? act[idx] : act[(size_t)b * IN + i];
    float wb = wbp[0], wsc = wsp[0];

    float sil = x / (1.f + __expf(-x));

    const float LO = -0.05f;
    const float INVH = 228.18181818181818f;  // 251/1.1
    float uf = (x - LO) * INVH;
    float fm = floorf(uf);
    float t = uf - fm;
    int M = (int)fm + 3;     // grid interval index: x in [GRID[M], GRID[M+1])

    bool valid = (M >= 0) && (M <= 256);

    float omt = 1.f - t;
    float t2 = t * t, t3 = t2 * t;
    const float S = 1.f / 6.f;
    float w0 = omt * omt * omt * S * wsc;
    float w1 = (3.f * t3 - 6.f * t2 + 4.f) * S * wsc;
    float w2 = (-3.f * t3 + 3.f * t2 + 3.f * t + 1.f) * S * wsc;
    float w3 = t3 * S * wsc;

    int js = M - 3;
    js = js < 0 ? 0 : js;
    js = js > (NB - 4) ? (NB - 4) : js;
    int d = js - (M - 3);    // shift of taps inside the clamped window, in [-3,3]

    float vp0 = selw(0 + d, w0, w1, w2, w3);
    float vp1 = selw(1 + d, w0, w1, w2, w3);
    float vp2 = selw(2 + d, w0, w1, w2, w3);
    float vp3 = selw(3 + d, w0, w1, w2, w3);

    if (!valid) js = -1;     // no spline contribution

    sjbuf[idx] = make_float2(sil * wb, __int_as_float(js));
    vbuf[idx] = make_float4(vp0, vp1, vp2, vp3);
}

// LDS-staged accum, XCD-aware.
// Block: 1024 threads = 128 b-lanes (x) * 8 o-rows (y); wave = 64 b-lanes of one o.
// Grid: (32 o-tiles [FAST -> XCD = o_tile%8], 16 b-tiles) -> all b-tiles of an o-tile
// on one XCD; 64 blocks/XCD = 2/CU, all co-resident; weights cross HBM once.
// Staging: 2 i-rows per barrier, double buffered; one wave stages one (o,i) row
// (64 lanes x 16B coalesced). Taps read from LDS (ds_read2), acc in registers.
// out/resid transposed [o][BATCH].
template<int IN, bool RES>
__global__ __launch_bounds__(1024, 8) void accum_lds(
    const float2* __restrict__ sjbuf,   // [i][BATCH]
    const float4* __restrict__ vbuf,    // [i][BATCH]
    const float* __restrict__ bw,       // [o][IN]
    const float* __restrict__ sw,       // [o][IN][254]
    const float* __restrict__ resid,    // [o][BATCH]
    float* __restrict__ out)            // [o][BATCH]
{
    int bx = threadIdx.x;               // 0..127
    int g  = threadIdx.y;               // 0..7
    int b  = blockIdx.y * 128 + bx;
    int o0 = blockIdx.x * 8;
    int o  = o0 + g;

    __shared__ float buf[2][2][8][256]; // 32 KB: [dbuf][i_sub][o-row][taps]

    // staging role: wave r stages row (o0+oo, i+isub), 4 floats per lane
    int t    = g * 128 + bx;            // 0..1023
    int r    = t >> 6;                  // 0..15
    int isub = r >> 3;                  // 0..1
    int oo   = r & 7;                   // 0..7
    int c    = (t & 63) << 2;           // 0,4,...,252
    bool full = (c < 252);              // c==252: only 2 floats remain (row=254)

    const float* srow = sw + (size_t)(o0 + oo) * IN * NB;

    // prologue: stage i = 0,1 into buf[0]
    {
        const float* sp = srow + (size_t)isub * NB + c;
        if (full) {
            f4u v4 = *(const f4u*)sp;
            float* dp = &buf[0][isub][oo][c];
            dp[0] = v4[0]; dp[1] = v4[1]; dp[2] = v4[2]; dp[3] = v4[3];
        } else {
            f2u v2 = *(const f2u*)sp;
            float* dp = &buf[0][isub][oo][c];
            dp[0] = v2[0]; dp[1] = v2[1];
        }
    }
    __syncthreads();

    float acc = 0.f;
    const float2* sjp = sjbuf + b;
    const float4* vvp = vbuf + b;
    const float* bwp  = bw + (size_t)o * IN;

    constexpr int S = IN / 2;
    for (int s = 0; s < S; s++) {
        int cur = s & 1;
        bool do_stage = (s + 1 < S);

        // issue next 2-row stage loads early (hide HBM/L2 latency under compute)
        f4u nv; f2u nv2;
        if (do_stage) {
            const float* sp = srow + ((size_t)(2 * (s + 1)) + isub) * NB + c;
            if (full) nv = *(const f4u*)sp;
            else      nv2 = *(const f2u*)sp;
        }

        // compute the 2 staged i's from buf[cur]
#pragma unroll
        for (int is = 0; is < 2; is++) {
            int i = 2 * s + is;
            float2 sj = sjp[(size_t)i * BATCH];
            int j = __float_as_int(sj.y);
            acc += sj.x * bwp[i];                     // base path (bw wave-uniform)
            if (j >= 0) {
                float4 v = vvp[(size_t)i * BATCH];
                const float* rp = &buf[cur][is][g][0];
                acc += v.x * rp[j] + v.y * rp[j + 1] + v.z * rp[j + 2] + v.w * rp[j + 3];
            }
        }

        // write next buffer, one barrier per 2-i step
        if (do_stage) {
            float* dp = &buf[cur ^ 1][isub][oo][c];
            if (full) { dp[0] = nv[0]; dp[1] = nv[1]; dp[2] = nv[2]; dp[3] = nv[3]; }
            else      { dp[0] = nv2[0]; dp[1] = nv2[1]; }
        }
        __syncthreads();
    }

    size_t oidx = (size_t)o * BATCH + b;
    float rr = RES ? resid[oidx] : 0.f;
    out[oidx] = acc + rr;
}

// Final layer: out=1, f32 weights. 64 lanes per batch row, shuffle-reduce.
__global__ __launch_bounds__(256) void out_kernel(
    const float2* __restrict__ sjbuf, const float4* __restrict__ vbuf,
    const float* __restrict__ bw, const float* __restrict__ sw,
    float* __restrict__ out)
{
    int tid = threadIdx.x;
    int bl = tid >> 6;
    int ig = tid & 63;
    int b = blockIdx.x * 4 + bl;

    float acc = 0.f;
    for (int ii = ig; ii < 256; ii += 64) {
        float2 sj = sjbuf[ii * BATCH + b];
        int j = __float_as_int(sj.y);
        acc += sj.x * bw[ii];
        if (j >= 0) {
            float4 v = vbuf[ii * BATCH + b];
            const float* p = sw + (size_t)ii * NB + j;
            acc += v.x * p[0] + v.y * p[1] + v.z * p[2] + v.w * p[3];
        }
    }
#pragma unroll
    for (int dlt = 32; dlt >= 1; dlt >>= 1) acc += __shfl_down(acc, dlt, 64);
    if (ig == 0) out[b] = acc;
}

extern "C" void kernel_launch(void* const* d_in, const int* in_sizes, int n_in,
                              void* d_out, int out_size, void* d_ws, size_t ws_size,
                              hipStream_t stream)
{
    const float* x   = (const float*)d_in[0];
    const float* bw0 = (const float*)d_in[1];
    const float* sw0 = (const float*)d_in[2];
    const float* wb0 = (const float*)d_in[3];
    const float* ws0 = (const float*)d_in[4];
    const float* bw1 = (const float*)d_in[5];
    const float* sw1 = (const float*)d_in[6];
    const float* wb1 = (const float*)d_in[7];
    const float* ws1 = (const float*)d_in[8];
    const float* bw2 = (const float*)d_in[9];
    const float* sw2 = (const float*)d_in[10];
    const float* wb2 = (const float*)d_in[11];
    const float* ws2 = (const float*)d_in[12];
    const float* bw3 = (const float*)d_in[13];
    const float* sw3 = (const float*)d_in[14];
    const float* wb3 = (const float*)d_in[15];
    const float* ws3 = (const float*)d_in[16];

    char* ws = (char*)d_ws;
    float4* vbuf  = (float4*)(ws);                        // 8 MB
    float2* sjbuf = (float2*)(ws + 8  * 1024 * 1024);     // 4 MB
    float*  hA    = (float*)(ws + 12 * 1024 * 1024);      // 2 MB  ([o][b] layout)
    float*  hB    = (float*)(ws + 14 * 1024 * 1024);      // 2 MB  ([o][b] layout)

    float* out = (float*)d_out;

    dim3 ablk(128, 8);    // 1024 threads: 128 b-lanes x 8 o-rows
    dim3 agrd(32, 16);    // o-tile FAST (XCD-affine), 16 b-tiles

    // Layer 0: 64 -> 256 (x is [b][64], all in-grid)
    basis_kernel<false><<<(BATCH * 64 + 255) / 256, 256, 0, stream>>>(x, 64, wb0, ws0, sjbuf, vbuf);
    accum_lds<64, false><<<agrd, ablk, 0, stream>>>(sjbuf, vbuf, bw0, sw0, nullptr, hA);

    // Layer 1: 256 -> 256, residual (hA is [o][b] == [i][b] for next layer)
    basis_kernel<true><<<(BATCH * 256 + 255) / 256, 256, 0, stream>>>(hA, 256, wb1, ws1, sjbuf, vbuf);
    accum_lds<256, true><<<agrd, ablk, 0, stream>>>(sjbuf, vbuf, bw1, sw1, hA, hB);

    // Layer 2: 256 -> 256, residual
    basis_kernel<true><<<(BATCH * 256 + 255) / 256, 256, 0, stream>>>(hB, 256, wb2, ws2, sjbuf, vbuf);
    accum_lds<256, true><<<agrd, ablk, 0, stream>>>(sjbuf, vbuf, bw2, sw2, hB, hA);

    // Layer 3: 256 -> 1
    basis_kernel<true><<<(BATCH * 256 + 255) / 256, 256, 0, stream>>>(hA, 256, wb3, ws3, sjbuf, vbuf);
    out_kernel<<<BATCH / 4, 256, 0, stream>>>(sjbuf, vbuf, bw3, sw3, out);
}

// Round 9
// 257.429 us; speedup vs baseline: 2.4144x; 2.3137x over previous
//
#include <hip/hip_runtime.h>

#define BATCH 2048
#define NB 254

typedef float f4u __attribute__((ext_vector_type(4), aligned(4)));

__device__ __forceinline__ float selw(int pd, float w0, float w1, float w2, float w3) {
    return (pd == 0) ? w0 : (pd == 1) ? w1 : (pd == 2) ? w2 : (pd == 3) ? w3 : 0.f;
}

// Shared basis math: given x, produce s-multiplier-free tap weights (scaled by wsc),
// window start js (or -1 if x outside grid), and silu(x).
__device__ __forceinline__ void basis_math(
    float x, float wsc, float& sil, int& js,
    float& vp0, float& vp1, float& vp2, float& vp3)
{
    sil = x / (1.f + __expf(-x));

    const float LO = -0.05f;
    const float INVH = 228.18181818181818f;  // 251/1.1
    float uf = (x - LO) * INVH;
    float fm = floorf(uf);
    float t = uf - fm;
    int M = (int)fm + 3;     // grid interval index

    bool valid = (M >= 0) && (M <= 256);

    float omt = 1.f - t;
    float t2 = t * t, t3 = t2 * t;
    const float S = 1.f / 6.f;
    float w0 = omt * omt * omt * S * wsc;
    float w1 = (3.f * t3 - 6.f * t2 + 4.f) * S * wsc;
    float w2 = (-3.f * t3 + 3.f * t2 + 3.f * t + 1.f) * S * wsc;
    float w3 = t3 * S * wsc;

    js = M - 3;
    js = js < 0 ? 0 : js;
    js = js > (NB - 4) ? (NB - 4) : js;
    int d = js - (M - 3);

    vp0 = selw(0 + d, w0, w1, w2, w3);
    vp1 = selw(1 + d, w0, w1, w2, w3);
    vp2 = selw(2 + d, w0, w1, w2, w3);
    vp3 = selw(3 + d, w0, w1, w2, w3);

    if (!valid) js = -1;
}

// Layer-0 basis: x is [b][64]; outputs in [i][BATCH] layout for the L0 accum.
__global__ __launch_bounds__(256) void basis_kernel(
    const float* __restrict__ act, int IN,
    const float* __restrict__ wbp, const float* __restrict__ wsp,
    float2* __restrict__ sjbuf, float4* __restrict__ vbuf)
{
    int idx = blockIdx.x * 256 + threadIdx.x;
    int total = BATCH * IN;
    if (idx >= total) return;
    int i = idx / BATCH;
    int b = idx - i * BATCH;

    float x = act[(size_t)b * IN + i];
    float wb = wbp[0], wsc = wsp[0];

    float sil; int js; float vp0, vp1, vp2, vp3;
    basis_math(x, wsc, sil, js, vp0, vp1, vp2, vp3);

    sjbuf[idx] = make_float2(sil * wb, __int_as_float(js));
    vbuf[idx] = make_float4(vp0, vp1, vp2, vp3);
}

// L0 accum (reads precomputed sjbuf/vbuf). Output transposed [o][BATCH].
template<int IN, int OT, bool RES, int IG, int BT>
__global__ __launch_bounds__(BT * IG) void accum_f32(
    const float2* __restrict__ sjbuf, const float4* __restrict__ vbuf,
    const float* __restrict__ bw, const float* __restrict__ sw,
    const float* __restrict__ resid, float* __restrict__ out)
{
    int bx = threadIdx.x;
    int g  = threadIdx.y;
    int b  = blockIdx.y * BT + bx;
    int o0 = blockIdx.x * OT;

    float acc[OT];
#pragma unroll
    for (int k = 0; k < OT; k++) acc[k] = 0.f;

    const size_t ostride = (size_t)IN * NB;
    const int CH = IN / IG;
    const int i0 = g * CH;

    for (int ii = 0; ii < CH; ii++) {
        int i = i0 + ii;
        float2 sj = sjbuf[i * BATCH + b];
        int j = __float_as_int(sj.y);
        float s = sj.x;
        const float* bq = bw + (size_t)o0 * IN + i;

#pragma unroll
        for (int oo = 0; oo < OT; oo++)
            acc[oo] += s * bq[oo * IN];

        if (j >= 0) {
            float4 v = vbuf[i * BATCH + b];
            const float* p = sw + (size_t)(o0 * IN + i) * NB + j;
            f4u wreg[OT];
#pragma unroll
            for (int oo = 0; oo < OT; oo++)
                wreg[oo] = *(const f4u*)(p + (size_t)oo * ostride);
#pragma unroll
            for (int oo = 0; oo < OT; oo++)
                acc[oo] += v.x * wreg[oo][0] + v.y * wreg[oo][1] + v.z * wreg[oo][2] + v.w * wreg[oo][3];
        }
    }

    __shared__ float lds[OT * (IG - 1) * BT];
    if (g > 0) {
#pragma unroll
        for (int oo = 0; oo < OT; oo++)
            lds[(oo * (IG - 1) + (g - 1)) * BT + bx] = acc[oo];
    }
    __syncthreads();
    if (g == 0) {
#pragma unroll
        for (int oo = 0; oo < OT; oo++) {
            float a = acc[oo];
            for (int gg = 1; gg < IG; gg++)
                a += lds[(oo * (IG - 1) + (gg - 1)) * BT + bx];
            size_t oidx = (size_t)(o0 + oo) * BATCH + b;
            float r = RES ? resid[oidx] : 0.f;
            out[oidx] = a + r;
        }
    }
}

// Fused hidden layer: basis computed inline from act [i][BATCH]; residual = act [o][BATCH].
// Block: BT b-lanes (x) * IG i-groups (y). Output transposed [o][BATCH].
template<int IN, int OT, int IG, int BT>
__global__ __launch_bounds__(BT * IG) void fused_accum(
    const float* __restrict__ act,      // [i][BATCH], also residual as [o][BATCH]
    const float* __restrict__ wbp, const float* __restrict__ wsp,
    const float* __restrict__ bw, const float* __restrict__ sw,
    float* __restrict__ out)            // [o][BATCH]
{
    int bx = threadIdx.x;
    int g  = threadIdx.y;
    int b  = blockIdx.y * BT + bx;
    int o0 = blockIdx.x * OT;

    float wb = wbp[0], wsc = wsp[0];

    float acc[OT];
#pragma unroll
    for (int k = 0; k < OT; k++) acc[k] = 0.f;

    const size_t ostride = (size_t)IN * NB;
    const int CH = IN / IG;
    const int i0 = g * CH;

    for (int ii = 0; ii < CH; ii++) {
        int i = i0 + ii;
        float x = act[(size_t)i * BATCH + b];       // coalesced (4 lines/wave)

        float sil; int j; float vp0, vp1, vp2, vp3;
        basis_math(x, wsc, sil, j, vp0, vp1, vp2, vp3);
        float s = sil * wb;

        const float* bq = bw + (size_t)o0 * IN + i;
#pragma unroll
        for (int oo = 0; oo < OT; oo++)
            acc[oo] += s * bq[oo * IN];

        if (j >= 0) {
            const float* p = sw + (size_t)(o0 * IN + i) * NB + j;
            f4u wreg[OT];
#pragma unroll
            for (int oo = 0; oo < OT; oo++)
                wreg[oo] = *(const f4u*)(p + (size_t)oo * ostride);
#pragma unroll
            for (int oo = 0; oo < OT; oo++)
                acc[oo] += vp0 * wreg[oo][0] + vp1 * wreg[oo][1] + vp2 * wreg[oo][2] + vp3 * wreg[oo][3];
        }
    }

    __shared__ float lds[OT * (IG - 1) * BT];
    if (g > 0) {
#pragma unroll
        for (int oo = 0; oo < OT; oo++)
            lds[(oo * (IG - 1) + (g - 1)) * BT + bx] = acc[oo];
    }
    __syncthreads();
    if (g == 0) {
#pragma unroll
        for (int oo = 0; oo < OT; oo++) {
            float a = acc[oo];
            for (int gg = 1; gg < IG; gg++)
                a += lds[(oo * (IG - 1) + (gg - 1)) * BT + bx];
            size_t oidx = (size_t)(o0 + oo) * BATCH + b;
            out[oidx] = a + act[oidx];              // residual
        }
    }
}

// Fused final layer (256 -> 1): basis inline, lane = b (coalesced act reads),
// 16 waves split i, LDS reduce. grid = BATCH/64 blocks x 1024 threads.
__global__ __launch_bounds__(1024) void out_fused(
    const float* __restrict__ act,      // [i][BATCH]
    const float* __restrict__ wbp, const float* __restrict__ wsp,
    const float* __restrict__ bw, const float* __restrict__ sw,
    float* __restrict__ out)
{
    int lane = threadIdx.x & 63;
    int w    = threadIdx.x >> 6;        // 0..15
    int b    = blockIdx.x * 64 + lane;

    float wb = wbp[0], wsc = wsp[0];
    float acc = 0.f;

#pragma unroll 4
    for (int k = 0; k < 16; k++) {
        int i = w * 16 + k;
        float x = act[(size_t)i * BATCH + b];       // coalesced

        float sil; int j; float vp0, vp1, vp2, vp3;
        basis_math(x, wsc, sil, j, vp0, vp1, vp2, vp3);

        acc += sil * wb * bw[i];
        if (j >= 0) {
            const float* p = sw + (size_t)i * NB + j;
            acc += vp0 * p[0] + vp1 * p[1] + vp2 * p[2] + vp3 * p[3];
        }
    }

    __shared__ float red[16][64];
    red[w][lane] = acc;
    __syncthreads();
    if (w == 0) {
        float a = acc;
        for (int k = 1; k < 16; k++) a += red[k][lane];
        out[b] = a;
    }
}

extern "C" void kernel_launch(void* const* d_in, const int* in_sizes, int n_in,
                              void* d_out, int out_size, void* d_ws, size_t ws_size,
                              hipStream_t stream)
{
    const float* x   = (const float*)d_in[0];
    const float* bw0 = (const float*)d_in[1];
    const float* sw0 = (const float*)d_in[2];
    const float* wb0 = (const float*)d_in[3];
    const float* ws0 = (const float*)d_in[4];
    const float* bw1 = (const float*)d_in[5];
    const float* sw1 = (const float*)d_in[6];
    const float* wb1 = (const float*)d_in[7];
    const float* ws1 = (const float*)d_in[8];
    const float* bw2 = (const float*)d_in[9];
    const float* sw2 = (const float*)d_in[10];
    const float* wb2 = (const float*)d_in[11];
    const float* ws2 = (const float*)d_in[12];
    const float* bw3 = (const float*)d_in[13];
    const float* sw3 = (const float*)d_in[14];
    const float* wb3 = (const float*)d_in[15];
    const float* ws3 = (const float*)d_in[16];

    char* ws = (char*)d_ws;
    float4* vbuf  = (float4*)(ws);                        // L0 basis: 2 MB
    float2* sjbuf = (float2*)(ws + 8  * 1024 * 1024);     // L0 basis: 1 MB
    float*  hA    = (float*)(ws + 12 * 1024 * 1024);      // 2 MB ([o][b])
    float*  hB    = (float*)(ws + 14 * 1024 * 1024);      // 2 MB ([o][b])

    float* out = (float*)d_out;

    dim3 ablk(64, 8);     // 512 threads: 64 b-lanes x 8 i-groups
    dim3 agrd(32, 32);    // 32 o-tiles x 32 b-tiles

    // Layer 0: 64 -> 256 (x is [b][64]) — separate basis (fused reads would be divergent)
    basis_kernel<<<(BATCH * 64 + 255) / 256, 256, 0, stream>>>(x, 64, wb0, ws0, sjbuf, vbuf);
    accum_f32<64, 8, false, 8, 64><<<agrd, ablk, 0, stream>>>(sjbuf, vbuf, bw0, sw0, nullptr, hA);

    // Layer 1: 256 -> 256, residual — fused basis
    fused_accum<256, 8, 8, 64><<<agrd, ablk, 0, stream>>>(hA, wb1, ws1, bw1, sw1, hB);

    // Layer 2: 256 -> 256, residual — fused basis
    fused_accum<256, 8, 8, 64><<<agrd, ablk, 0, stream>>>(hB, wb2, ws2, bw2, sw2, hA);

    // Layer 3: 256 -> 1 — fused basis + reduce
    out_fused<<<BATCH / 64, 1024, 0, stream>>>(hA, wb3, ws3, bw3, sw3, out);
}